// Round 10
// baseline (7028.207 us; speedup 1.0000x reference)
//
#include <hip/hip_runtime.h>
#include <hip/hip_bf16.h>
#include <stdint.h>

typedef __bf16 bf16;
typedef __bf16 bf16x8 __attribute__((ext_vector_type(8)));
typedef float f32x4 __attribute__((ext_vector_type(4)));

typedef uint32_t __attribute__((address_space(1))) * gptr_as1;
typedef uint32_t __attribute__((address_space(3))) * lptr_as3;

__device__ __forceinline__ void async16(const void* g, void* l) {
    __builtin_amdgcn_global_load_lds((gptr_as1)(uintptr_t)g,
                                     (lptr_as3)(uintptr_t)l,
                                     16, 0, 0);
}

__device__ __forceinline__ void bar() {
    asm volatile("" ::: "memory");
    __builtin_amdgcn_s_barrier();
    asm volatile("" ::: "memory");
}

// ---------------------------------------------------------------- cvt f32->bf16
__global__ void cvt_f32_bf16_kernel(const float* __restrict__ src,
                                    bf16* __restrict__ dst, int n8) {
    int i = blockIdx.x * blockDim.x + threadIdx.x;
    if (i >= n8) return;
    const float4* s = reinterpret_cast<const float4*>(src);
    float4 a = s[2 * (size_t)i], b = s[2 * (size_t)i + 1];
    bf16x8 v;
    v[0] = (bf16)a.x; v[1] = (bf16)a.y; v[2] = (bf16)a.z; v[3] = (bf16)a.w;
    v[4] = (bf16)b.x; v[5] = (bf16)b.y; v[6] = (bf16)b.z; v[7] = (bf16)b.w;
    *reinterpret_cast<bf16x8*>(dst + (size_t)i * 8) = v;
}

// cvt + 16-row interleave: src row r (of DHID) -> dst row (r/16)*32 + sel*16 + r%16.
__global__ void cvt_ilv_kernel(const float* __restrict__ src,
                               bf16* __restrict__ dst, int n8, int sel) {
    int i = blockIdx.x * blockDim.x + threadIdx.x;
    if (i >= n8) return;
    const int row = i >> 8;          // / 256  (DIN=2048 -> 256 chunks/row)
    const int c = i & 255;
    const int drow = ((row >> 4) << 5) + (sel << 4) + (row & 15);
    const float4* s = reinterpret_cast<const float4*>(src);
    float4 a = s[2 * (size_t)i], b = s[2 * (size_t)i + 1];
    bf16x8 v;
    v[0] = (bf16)a.x; v[1] = (bf16)a.y; v[2] = (bf16)a.z; v[3] = (bf16)a.w;
    v[4] = (bf16)b.x; v[5] = (bf16)b.y; v[6] = (bf16)b.z; v[7] = (bf16)b.w;
    *reinterpret_cast<bf16x8*>(dst + ((size_t)drow * 256 + c) * 8) = v;
}

// ---------------------------------------------------------------- 256^2 GEMM, 4 fat waves (128x128 wave tile)
// C = A[M,K] * B[N,K]^T. BM=BN=256, BK=64. 256 thr / 4 waves (2x2),
// wave tile 128x128, acc[8][8] f32x4 = 256 regs (unified VGPR/AGPR).
// WHY: LDS-read traffic per FLOP is set by wave-tile shape:
// (waveM+waveN)*BK bytes per waveM*waveN*BK*2 FLOP. 128x128 -> 4 MFMA per
// ds_read_b128 vs 2.67 at 128x64. Per CU-tile: MFMA 2483 cyc > LDS 1536 cyc
// -> MFMA-dominant (every prior round had LDS ~= MFMA serialized at ~50%).
// LDS: dbuf x (A 32KB + B 32KB) = 128KB, 1 block/CU, 1 wave/SIMD.
// Loop: [stage kt+1 -> other buf; read ks0 (16 b128); lgkm; MFMA ks0 (64);
//        read ks1 (compiler weaves under MFMA0); lgkm; MFMA ks1 (64);
//        vmcnt(0) (~free: issued a full tile ago); bar]
//  WAR: stage(kt+1) targets buffer whose kt-1 reads were lgkm-retired before
//       each wave passed the previous barrier.
//  RAW: vmcnt(0)+bar precede kt+1's reads.
// Swizzle lds_byte = row*128 + (colb ^ ((row&7)<<4)) (proven conflict-free);
// gload_lds dest linear, global source pre-swizzled (rule #21).
// EPI=0: bf16(gelu(acc*s1)) | EPI=1: f32(acc*s1) | EPI=2: swiglu, 16-col interleave.
template <int EPI, int K>
__global__ __launch_bounds__(256, 1)
void gemmfat(const bf16* __restrict__ A, const bf16* __restrict__ B,
             void* __restrict__ Cout, const float* __restrict__ s1p,
             const float* __restrict__ s2p, int N, int ldh) {
    __shared__ __align__(16) char sm[131072];

    const int tid = threadIdx.x;
    const int w = tid >> 6, l = tid & 63;
    const int wr = w >> 1, wc = w & 1;   // 2x2 wave grid; wave tile 128x128

    const int gx = gridDim.x;            // N/256
    const int nwg = gx * (int)gridDim.y;
    const int orig = blockIdx.y * gx + blockIdx.x;
    const int wg = (orig & 7) * (nwg >> 3) + (orig >> 3);
    const int bm = wg / gx, bn = wg % gx;

    constexpr int NT = K / 64;

    f32x4 acc[8][8] = {};

    // buffer p: A at p*65536, B at p*65536 + 32768
    const int arow = bm * 256, brow = bn * 256;

    const int srow_in = l >> 3;
    const int scolb = ((l & 7) ^ srow_in) << 4;
    auto STAGE = [&](char* ldsT, const bf16* g, int grow0, int kt, int r0) {
        // 4 waves x 8 rows = 32 rows per call
        const int rr = r0 + w * 8 + srow_in;
        const char* gp = (const char*)(g + (size_t)(grow0 + rr) * K + kt * 64) + scolb;
        async16(gp, ldsT + r0 * 128 + w * 1024);
    };
    auto STAGE_TILE = [&](int kt) {
        char* base = sm + (kt & 1) * 65536;
#pragma unroll
        for (int r = 0; r < 8; ++r) STAGE(base, A, arow, kt, r * 32);
#pragma unroll
        for (int r = 0; r < 8; ++r) STAGE(base + 32768, B, brow, kt, r * 32);
    };

    const int rlane = l & 15;
    const int chi = (l >> 4) << 4;
    auto FRAG = [&](const char* tb, int row, int ks) -> bf16x8 {
        const int cb = (ks * 64 + chi) ^ ((row & 7) << 4);
        return *reinterpret_cast<const bf16x8*>(tb + row * 128 + cb);
    };

    // ---- prologue
    STAGE_TILE(0);
    asm volatile("s_waitcnt vmcnt(0)" ::: "memory");
    bar();

#pragma unroll 1
    for (int kt = 0; kt < NT; ++kt) {
        const char* bA = sm + (kt & 1) * 65536;
        const char* bB = bA + 32768;
        if (kt + 1 < NT) STAGE_TILE(kt + 1);

        bf16x8 av[8], bv[8];
        // ks = 0
#pragma unroll
        for (int i = 0; i < 8; ++i)
            av[i] = FRAG(bA, wr * 128 + i * 16 + rlane, 0);
#pragma unroll
        for (int j = 0; j < 8; ++j)
            bv[j] = FRAG(bB, wc * 128 + j * 16 + rlane, 0);
        asm volatile("s_waitcnt lgkmcnt(0)" ::: "memory");
        __builtin_amdgcn_sched_barrier(0);
        __builtin_amdgcn_s_setprio(1);
#pragma unroll
        for (int i = 0; i < 8; ++i)
#pragma unroll
            for (int j = 0; j < 8; ++j)
                acc[i][j] = __builtin_amdgcn_mfma_f32_16x16x32_bf16(av[i], bv[j], acc[i][j], 0, 0, 0);
        __builtin_amdgcn_s_setprio(0);
        // ks = 1 (reads weave under / after MFMA0 — no sched fence before them)
        bf16x8 av1[8], bv1[8];
#pragma unroll
        for (int i = 0; i < 8; ++i)
            av1[i] = FRAG(bA, wr * 128 + i * 16 + rlane, 1);
#pragma unroll
        for (int j = 0; j < 8; ++j)
            bv1[j] = FRAG(bB, wc * 128 + j * 16 + rlane, 1);
        asm volatile("s_waitcnt lgkmcnt(0)" ::: "memory");
        __builtin_amdgcn_sched_barrier(0);
        __builtin_amdgcn_s_setprio(1);
#pragma unroll
        for (int i = 0; i < 8; ++i)
#pragma unroll
            for (int j = 0; j < 8; ++j)
                acc[i][j] = __builtin_amdgcn_mfma_f32_16x16x32_bf16(av1[i], bv1[j], acc[i][j], 0, 0, 0);
        __builtin_amdgcn_s_setprio(0);
        asm volatile("s_waitcnt vmcnt(0)" ::: "memory");
        bar();
    }

    const float s1 = s1p[0];
    const int r0 = bm * 256 + wr * 128 + ((l >> 4) << 2);
    if constexpr (EPI == 2) {
        const float s2 = s2p[0];
        // gate col j=2jp, value col j=2jp+1 (16-col interleave)
        // h col = (bn*8 + wc*4 + jp)*16 + rlane
        const int hcb = (bn * 8 + wc * 4) * 16 + rlane;
#pragma unroll
        for (int i = 0; i < 8; ++i)
#pragma unroll
            for (int jp = 0; jp < 4; ++jp)
#pragma unroll
                for (int q = 0; q < 4; ++q) {
                    float g = acc[i][2 * jp][q] * s1;
                    float v = acc[i][2 * jp + 1][q] * s2;
                    float sig = 1.0f / (1.0f + __expf(-g));
                    ((bf16*)Cout)[(size_t)(r0 + i * 16 + q) * ldh + hcb + jp * 16] =
                        (bf16)(g * sig * v);
                }
    } else {
        const int c0 = bn * 256 + wc * 128 + rlane;
#pragma unroll
        for (int i = 0; i < 8; ++i)
#pragma unroll
            for (int j = 0; j < 8; ++j)
#pragma unroll
                for (int q = 0; q < 4; ++q) {
                    float v = acc[i][j][q] * s1;
                    size_t idx = (size_t)(r0 + i * 16 + q) * N + (c0 + j * 16);
                    if constexpr (EPI == 0) {
                        float g = 0.5f * v * (1.0f + erff(v * 0.70710678118654752f));
                        ((bf16*)Cout)[idx] = (bf16)g;
                    } else {
                        ((float*)Cout)[idx] = v;
                    }
                }
    }
}

// ---------------------------------------------------------------- launch
extern "C" void kernel_launch(void* const* d_in, const int* in_sizes, int n_in,
                              void* d_out, int out_size, void* d_ws, size_t ws_size,
                              hipStream_t stream) {
    constexpr int NTOK = 8192, DIN = 2048, DHID = 8192;

    const float* x  = (const float*)d_in[0];
    const float* W1 = (const float*)d_in[1];
    const float* W2 = (const float*)d_in[2];
    const float* Wh = (const float*)d_in[3];
    const float* W3 = (const float*)d_in[4];
    const float* s1 = (const float*)d_in[5];
    const float* s2 = (const float*)d_in[6];
    const float* sh = (const float*)d_in[7];
    const float* s3 = (const float*)d_in[8];
    float* out = (float*)d_out;

    char* ws = (char*)d_ws;
    size_t off = 0;
    bf16* xb   = (bf16*)(ws + off); off += (size_t)NTOK * DIN * 2;
    bf16* w12b = (bf16*)(ws + off); off += (size_t)2 * DHID * DIN * 2;
    bf16* w3b  = (bf16*)(ws + off); off += (size_t)DIN * DHID * 2;
    bf16* whb  = (bf16*)(ws + off); off += (size_t)DHID * DHID * 2;
    bf16* h1   = (bf16*)(ws + off); off += (size_t)NTOK * DHID * 2;
    bf16* h2   = (bf16*)(ws + off); off += (size_t)NTOK * DHID * 2;
    if (ws_size < off) return;

    auto cvt = [&](const float* s, bf16* d, size_t n) {
        int n8 = (int)(n / 8);
        cvt_f32_bf16_kernel<<<(n8 + 255) / 256, 256, 0, stream>>>(s, d, n8);
    };
    cvt(x,  xb,  (size_t)NTOK * DIN);
    cvt(Wh, whb, (size_t)DHID * DHID);
    cvt(W3, w3b, (size_t)DIN * DHID);
    {
        int n8 = (int)((size_t)DHID * DIN / 8);
        cvt_ilv_kernel<<<(n8 + 255) / 256, 256, 0, stream>>>(W1, w12b, n8, 0);
        cvt_ilv_kernel<<<(n8 + 255) / 256, 256, 0, stream>>>(W2, w12b, n8, 1);
    }

    // GEMM1+2 fused: C[8192, 16384] over interleaved W12, SwiGLU epilogue -> h1
    gemmfat<2, DIN><<<dim3(2 * DHID / 256, NTOK / 256), 256, 0, stream>>>(
        xb, w12b, h1, s1, s2, 2 * DHID, DHID);
    // hidden GEMM + gelu -> h2
    gemmfat<0, DHID><<<dim3(DHID / 256, NTOK / 256), 256, 0, stream>>>(
        h1, whb, h2, sh, sh, DHID, DHID);
    // output GEMM -> out (f32)
    gemmfat<1, DHID><<<dim3(DIN / 256, NTOK / 256), 256, 0, stream>>>(
        h2, w3b, out, s3, s3, DIN, DIN);
}

// Round 11
// 1722.828 us; speedup vs baseline: 4.0795x; 4.0795x over previous
//
#include <hip/hip_runtime.h>
#include <hip/hip_bf16.h>
#include <stdint.h>

typedef __bf16 bf16;
typedef __bf16 bf16x8 __attribute__((ext_vector_type(8)));
typedef float f32x4 __attribute__((ext_vector_type(4)));

typedef uint32_t __attribute__((address_space(1))) * gptr_as1;
typedef uint32_t __attribute__((address_space(3))) * lptr_as3;

__device__ __forceinline__ void async16(const void* g, void* l) {
    __builtin_amdgcn_global_load_lds((gptr_as1)(uintptr_t)g,
                                     (lptr_as3)(uintptr_t)l,
                                     16, 0, 0);
}

__device__ __forceinline__ void bar() {
    asm volatile("" ::: "memory");
    __builtin_amdgcn_s_barrier();
    asm volatile("" ::: "memory");
}

// ---------------------------------------------------------------- cvt f32->bf16
__global__ void cvt_f32_bf16_kernel(const float* __restrict__ src,
                                    bf16* __restrict__ dst, int n8) {
    int i = blockIdx.x * blockDim.x + threadIdx.x;
    if (i >= n8) return;
    const float4* s = reinterpret_cast<const float4*>(src);
    float4 a = s[2 * (size_t)i], b = s[2 * (size_t)i + 1];
    bf16x8 v;
    v[0] = (bf16)a.x; v[1] = (bf16)a.y; v[2] = (bf16)a.z; v[3] = (bf16)a.w;
    v[4] = (bf16)b.x; v[5] = (bf16)b.y; v[6] = (bf16)b.z; v[7] = (bf16)b.w;
    *reinterpret_cast<bf16x8*>(dst + (size_t)i * 8) = v;
}

// cvt + 16-row interleave: src row r (of DHID) -> dst row (r/16)*32 + sel*16 + r%16.
__global__ void cvt_ilv_kernel(const float* __restrict__ src,
                               bf16* __restrict__ dst, int n8, int sel) {
    int i = blockIdx.x * blockDim.x + threadIdx.x;
    if (i >= n8) return;
    const int row = i >> 8;          // / 256  (DIN=2048 -> 256 chunks/row)
    const int c = i & 255;
    const int drow = ((row >> 4) << 5) + (sel << 4) + (row & 15);
    const float4* s = reinterpret_cast<const float4*>(src);
    float4 a = s[2 * (size_t)i], b = s[2 * (size_t)i + 1];
    bf16x8 v;
    v[0] = (bf16)a.x; v[1] = (bf16)a.y; v[2] = (bf16)a.z; v[3] = (bf16)a.w;
    v[4] = (bf16)b.x; v[5] = (bf16)b.y; v[6] = (bf16)b.z; v[7] = (bf16)b.w;
    *reinterpret_cast<bf16x8*>(dst + ((size_t)drow * 256 + c) * 8) = v;
}

// ---------------------------------------------------------------- 256^2 GEMM, m201-faithful (m-half x k-half phases)
// C = A[M,K] * B[N,K]^T. 512 thr / 8 waves (2Mx4N), wave tile 128x64, BK=64.
// LDS: 2 dbuf x (A 32KB + B 32KB) = 128KB; swizzle lds_byte = row*128 +
// (colb ^ ((row&7)<<4)) (conflicts measured 0); gload_lds dest linear,
// global source pre-swizzled (rule #21).
// PHASES = (m-half, k-half) quadrants -> balanced same-phase reads 8/4/8/4
// (m201's "4 or 8 ds_reads/phase"), 16 MFMA/phase, one MFMA per acc element
// per phase (no intra-phase acc chains):
//   P1: read avE-ks0 (4) + bv-ks0 (4); MFMA acc[0-3][0-3]
//   P2: read avO-ks0 (4);              MFMA acc[4-7][0-3]
//   P3: read avE-ks1 (4) + bv-ks1 (4); MFMA acc[0-3][0-3]
//   P4: read avO-ks1 (4);              MFMA acc[4-7][0-3]
// Region read-phases: A-even {P1,P3}, A-odd {P2,P4}, B {P1,P3}.
// Stages: P1: A-odd(kt+1)->nA (WAR-safe: buf last read tile kt-1, drained at
// its barriers); P3 after reads: B-h0(kt+2)->cB (same-phase-after, write
// arrives >=300cy after ~12cy reads — HK pattern); P4: B-h1(kt+2)->cB +
// A-even(kt+2)->cA (strictly after last reads at P3).
// vmcnt(6) at end-P4: FIFO = [Aodd(kt+1)@P1, Bh0(kt+2)@P3, Bh1+Aev(kt+2)@P4],
// leaves the 6 kt+2 loads, lands Aodd(kt+1) and older => ALL of kt+1 present.
// Prologue: tile0 {Aev,Bh0,Bh1,Aodd} + tile1 {Aev,Bh0,Bh1}, vmcnt(6) lands
// tile0, leaves tile1's 6 = steady-state invariant. Tail: vmcnt(0) at NT-2.
// EPI=0: bf16(gelu(acc*s1)) | EPI=1: f32(acc*s1) | EPI=2: swiglu, 16-col interleave.
template <int EPI, int K>
__global__ __launch_bounds__(512, 1)
void gemm8p(const bf16* __restrict__ A, const bf16* __restrict__ B,
            void* __restrict__ Cout, const float* __restrict__ s1p,
            const float* __restrict__ s2p, int N, int ldh) {
    __shared__ __align__(16) char sm[131072];

    const int tid = threadIdx.x;
    const int w = tid >> 6, l = tid & 63;
    const int wr = w >> 2, wc = w & 3;

    const int gx = gridDim.x;
    const int nwg = gx * (int)gridDim.y;
    const int orig = blockIdx.y * gx + blockIdx.x;
    const int wg = (orig & 7) * (nwg >> 3) + (orig >> 3);
    const int bm = wg / gx, bn = wg % gx;

    constexpr int NT = K / 64;

    f32x4 acc[8][4] = {};

    char* const bufA0 = sm;
    char* const bufB0 = sm + 32768;
    char* const bufA1 = sm + 65536;
    char* const bufB1 = sm + 98304;
    const int arow = bm * 256, brow = bn * 256;

    const int srow_in = l >> 3;
    const int scolb = ((l & 7) ^ srow_in) << 4;
    auto STAGE = [&](char* ldsT, const bf16* g, int grow0, int kt, int r0) {
        const int rr = r0 + w * 8 + srow_in;
        const char* gp = (const char*)(g + (size_t)(grow0 + rr) * K + kt * 64) + scolb;
        async16(gp, ldsT + r0 * 128 + w * 1024);
    };

    const int rlane = l & 15;
    const int chi = (l >> 4) << 4;
    auto FRAG = [&](const char* tb, int row, int ks) -> bf16x8 {
        const int cb = (ks * 64 + chi) ^ ((row & 7) << 4);
        return *reinterpret_cast<const bf16x8*>(tb + row * 128 + cb);
    };

    // ---- prologue: tile0 {A-even, B-h0, B-h1, A-odd}; tile1 {A-even, B-h0, B-h1}
    STAGE(bufA0, A, arow, 0, 0);   STAGE(bufA0, A, arow, 0, 128);  // A-even(0)
    STAGE(bufB0, B, brow, 0, 0);   STAGE(bufB0, B, brow, 0, 64);   // B-h0(0)
    STAGE(bufB0, B, brow, 0, 128); STAGE(bufB0, B, brow, 0, 192);  // B-h1(0)
    STAGE(bufA0, A, arow, 0, 64);  STAGE(bufA0, A, arow, 0, 192);  // A-odd(0)
    STAGE(bufA1, A, arow, 1, 0);   STAGE(bufA1, A, arow, 1, 128);  // A-even(1)
    STAGE(bufB1, B, brow, 1, 0);   STAGE(bufB1, B, brow, 1, 64);   // B-h0(1)
    STAGE(bufB1, B, brow, 1, 128); STAGE(bufB1, B, brow, 1, 192);  // B-h1(1)
    asm volatile("s_waitcnt vmcnt(6)" ::: "memory");
    bar();

    char* cA = bufA0; char* cB = bufB0;
    char* nA = bufA1; char* nB = bufB1;

#pragma unroll 1
    for (int kt = 0; kt < NT; ++kt) {
        bf16x8 ae[4], ao[4], bv[4];
        // ---- P1 (8 reads): avE-ks0 + bv-ks0; stage A-odd(kt+1)->nA
#pragma unroll
        for (int i = 0; i < 4; ++i)
            ae[i] = FRAG(cA, wr * 128 + i * 16 + rlane, 0);
#pragma unroll
        for (int j = 0; j < 4; ++j)
            bv[j] = FRAG(cB, wc * 64 + j * 16 + rlane, 0);
        if (kt + 1 < NT) { STAGE(nA, A, arow, kt + 1, 64); STAGE(nA, A, arow, kt + 1, 192); }
        bar();
        asm volatile("s_waitcnt lgkmcnt(0)" ::: "memory");
        __builtin_amdgcn_sched_barrier(0);
        __builtin_amdgcn_s_setprio(1);
#pragma unroll
        for (int i = 0; i < 4; ++i)
#pragma unroll
            for (int j = 0; j < 4; ++j)
                acc[i][j] = __builtin_amdgcn_mfma_f32_16x16x32_bf16(ae[i], bv[j], acc[i][j], 0, 0, 0);
        __builtin_amdgcn_s_setprio(0);
        bar();
        // ---- P2 (4 reads): avO-ks0
#pragma unroll
        for (int i = 0; i < 4; ++i)
            ao[i] = FRAG(cA, wr * 128 + 64 + i * 16 + rlane, 0);
        bar();
        asm volatile("s_waitcnt lgkmcnt(0)" ::: "memory");
        __builtin_amdgcn_sched_barrier(0);
        __builtin_amdgcn_s_setprio(1);
#pragma unroll
        for (int i = 0; i < 4; ++i)
#pragma unroll
            for (int j = 0; j < 4; ++j)
                acc[4 + i][j] = __builtin_amdgcn_mfma_f32_16x16x32_bf16(ao[i], bv[j], acc[4 + i][j], 0, 0, 0);
        __builtin_amdgcn_s_setprio(0);
        bar();
        // ---- P3 (8 reads): avE-ks1 + bv-ks1; then stage B-h0(kt+2)->cB
#pragma unroll
        for (int i = 0; i < 4; ++i)
            ae[i] = FRAG(cA, wr * 128 + i * 16 + rlane, 1);
#pragma unroll
        for (int j = 0; j < 4; ++j)
            bv[j] = FRAG(cB, wc * 64 + j * 16 + rlane, 1);
        if (kt + 2 < NT) { STAGE(cB, B, brow, kt + 2, 0); STAGE(cB, B, brow, kt + 2, 64); }
        bar();
        asm volatile("s_waitcnt lgkmcnt(0)" ::: "memory");
        __builtin_amdgcn_sched_barrier(0);
        __builtin_amdgcn_s_setprio(1);
#pragma unroll
        for (int i = 0; i < 4; ++i)
#pragma unroll
            for (int j = 0; j < 4; ++j)
                acc[i][j] = __builtin_amdgcn_mfma_f32_16x16x32_bf16(ae[i], bv[j], acc[i][j], 0, 0, 0);
        __builtin_amdgcn_s_setprio(0);
        bar();
        // ---- P4 (4 reads): avO-ks1; stage B-h1(kt+2)->cB + A-even(kt+2)->cA
#pragma unroll
        for (int i = 0; i < 4; ++i)
            ao[i] = FRAG(cA, wr * 128 + 64 + i * 16 + rlane, 1);
        if (kt + 2 < NT) {
            STAGE(cB, B, brow, kt + 2, 128); STAGE(cB, B, brow, kt + 2, 192);
            STAGE(cA, A, arow, kt + 2, 0);   STAGE(cA, A, arow, kt + 2, 128);
        }
        bar();
        asm volatile("s_waitcnt lgkmcnt(0)" ::: "memory");
        __builtin_amdgcn_sched_barrier(0);
        __builtin_amdgcn_s_setprio(1);
#pragma unroll
        for (int i = 0; i < 4; ++i)
#pragma unroll
            for (int j = 0; j < 4; ++j)
                acc[4 + i][j] = __builtin_amdgcn_mfma_f32_16x16x32_bf16(ao[i], bv[j], acc[4 + i][j], 0, 0, 0);
        __builtin_amdgcn_s_setprio(0);
        if (kt == NT - 2) { asm volatile("s_waitcnt vmcnt(0)" ::: "memory"); }
        else              { asm volatile("s_waitcnt vmcnt(6)" ::: "memory"); }
        bar();
        char* t = cA; cA = nA; nA = t;
        t = cB; cB = nB; nB = t;
    }

    const float s1 = s1p[0];
    const int r0 = bm * 256 + wr * 128 + ((l >> 4) << 2);
    if constexpr (EPI == 2) {
        const float s2 = s2p[0];
        const int hcb = (bn * 8 + wc * 2) * 16 + rlane;
#pragma unroll
        for (int i = 0; i < 8; ++i)
#pragma unroll
            for (int jp = 0; jp < 2; ++jp)
#pragma unroll
                for (int q = 0; q < 4; ++q) {
                    float g = acc[i][2 * jp][q] * s1;
                    float v = acc[i][2 * jp + 1][q] * s2;
                    float sig = 1.0f / (1.0f + __expf(-g));
                    ((bf16*)Cout)[(size_t)(r0 + i * 16 + q) * ldh + hcb + jp * 16] =
                        (bf16)(g * sig * v);
                }
    } else {
        const int c0 = bn * 256 + wc * 64 + rlane;
#pragma unroll
        for (int i = 0; i < 8; ++i)
#pragma unroll
            for (int j = 0; j < 4; ++j)
#pragma unroll
                for (int q = 0; q < 4; ++q) {
                    float v = acc[i][j][q] * s1;
                    size_t idx = (size_t)(r0 + i * 16 + q) * N + (c0 + j * 16);
                    if constexpr (EPI == 0) {
                        float g = 0.5f * v * (1.0f + erff(v * 0.70710678118654752f));
                        ((bf16*)Cout)[idx] = (bf16)g;
                    } else {
                        ((float*)Cout)[idx] = v;
                    }
                }
    }
}

// ---------------------------------------------------------------- launch
extern "C" void kernel_launch(void* const* d_in, const int* in_sizes, int n_in,
                              void* d_out, int out_size, void* d_ws, size_t ws_size,
                              hipStream_t stream) {
    constexpr int NTOK = 8192, DIN = 2048, DHID = 8192;

    const float* x  = (const float*)d_in[0];
    const float* W1 = (const float*)d_in[1];
    const float* W2 = (const float*)d_in[2];
    const float* Wh = (const float*)d_in[3];
    const float* W3 = (const float*)d_in[4];
    const float* s1 = (const float*)d_in[5];
    const float* s2 = (const float*)d_in[6];
    const float* sh = (const float*)d_in[7];
    const float* s3 = (const float*)d_in[8];
    float* out = (float*)d_out;

    char* ws = (char*)d_ws;
    size_t off = 0;
    bf16* xb   = (bf16*)(ws + off); off += (size_t)NTOK * DIN * 2;
    bf16* w12b = (bf16*)(ws + off); off += (size_t)2 * DHID * DIN * 2;
    bf16* w3b  = (bf16*)(ws + off); off += (size_t)DIN * DHID * 2;
    bf16* whb  = (bf16*)(ws + off); off += (size_t)DHID * DHID * 2;
    bf16* h1   = (bf16*)(ws + off); off += (size_t)NTOK * DHID * 2;
    bf16* h2   = (bf16*)(ws + off); off += (size_t)NTOK * DHID * 2;
    if (ws_size < off) return;

    auto cvt = [&](const float* s, bf16* d, size_t n) {
        int n8 = (int)(n / 8);
        cvt_f32_bf16_kernel<<<(n8 + 255) / 256, 256, 0, stream>>>(s, d, n8);
    };
    cvt(x,  xb,  (size_t)NTOK * DIN);
    cvt(Wh, whb, (size_t)DHID * DHID);
    cvt(W3, w3b, (size_t)DIN * DHID);
    {
        int n8 = (int)((size_t)DHID * DIN / 8);
        cvt_ilv_kernel<<<(n8 + 255) / 256, 256, 0, stream>>>(W1, w12b, n8, 0);
        cvt_ilv_kernel<<<(n8 + 255) / 256, 256, 0, stream>>>(W2, w12b, n8, 1);
    }

    // GEMM1+2 fused: C[8192, 16384] over interleaved W12, SwiGLU epilogue -> h1
    gemm8p<2, DIN><<<dim3(2 * DHID / 256, NTOK / 256), 512, 0, stream>>>(
        xb, w12b, h1, s1, s2, 2 * DHID, DHID);
    // hidden GEMM + gelu -> h2
    gemm8p<0, DHID><<<dim3(DHID / 256, NTOK / 256), 512, 0, stream>>>(
        h1, whb, h2, sh, sh, DHID, DHID);
    // output GEMM -> out (f32)
    gemm8p<1, DHID><<<dim3(DIN / 256, NTOK / 256), 512, 0, stream>>>(
        h2, w3b, out, s3, s3, DIN, DIN);
}

// Round 13
// 1712.933 us; speedup vs baseline: 4.1030x; 1.0058x over previous
//
#include <hip/hip_runtime.h>
#include <hip/hip_bf16.h>
#include <stdint.h>

typedef __bf16 bf16;
typedef __bf16 bf16x8 __attribute__((ext_vector_type(8)));
typedef float f32x4 __attribute__((ext_vector_type(4)));

typedef uint32_t __attribute__((address_space(1))) * gptr_as1;
typedef uint32_t __attribute__((address_space(3))) * lptr_as3;

__device__ __forceinline__ void async16(const void* g, void* l) {
    __builtin_amdgcn_global_load_lds((gptr_as1)(uintptr_t)g,
                                     (lptr_as3)(uintptr_t)l,
                                     16, 0, 0);
}

__device__ __forceinline__ void bar() {
    asm volatile("" ::: "memory");
    __builtin_amdgcn_s_barrier();
    asm volatile("" ::: "memory");
}

// ---------------------------------------------------------------- cvt f32->bf16
__global__ void cvt_f32_bf16_kernel(const float* __restrict__ src,
                                    bf16* __restrict__ dst, int n8) {
    int i = blockIdx.x * blockDim.x + threadIdx.x;
    if (i >= n8) return;
    const float4* s = reinterpret_cast<const float4*>(src);
    float4 a = s[2 * (size_t)i], b = s[2 * (size_t)i + 1];
    bf16x8 v;
    v[0] = (bf16)a.x; v[1] = (bf16)a.y; v[2] = (bf16)a.z; v[3] = (bf16)a.w;
    v[4] = (bf16)b.x; v[5] = (bf16)b.y; v[6] = (bf16)b.z; v[7] = (bf16)b.w;
    *reinterpret_cast<bf16x8*>(dst + (size_t)i * 8) = v;
}

// cvt + 16-row interleave: src row r (of DHID) -> dst row (r/16)*32 + sel*16 + r%16.
__global__ void cvt_ilv_kernel(const float* __restrict__ src,
                               bf16* __restrict__ dst, int n8, int sel) {
    int i = blockIdx.x * blockDim.x + threadIdx.x;
    if (i >= n8) return;
    const int row = i >> 8;          // / 256  (DIN=2048 -> 256 chunks/row)
    const int c = i & 255;
    const int drow = ((row >> 4) << 5) + (sel << 4) + (row & 15);
    const float4* s = reinterpret_cast<const float4*>(src);
    float4 a = s[2 * (size_t)i], b = s[2 * (size_t)i + 1];
    bf16x8 v;
    v[0] = (bf16)a.x; v[1] = (bf16)a.y; v[2] = (bf16)a.z; v[3] = (bf16)a.w;
    v[4] = (bf16)b.x; v[5] = (bf16)b.y; v[6] = (bf16)b.z; v[7] = (bf16)b.w;
    *reinterpret_cast<bf16x8*>(dst + ((size_t)drow * 256 + c) * 8) = v;
}

// ---------------------------------------------------------------- 256^2 GEMM: R11 schedule + zero-VALU LDS reads
// C = A[M,K] * B[N,K]^T. 512 thr / 8 waves (2Mx4N), wave tile 128x64, BK=64.
// Schedule, staging, vmcnt ledger: IDENTICAL to R11 (passed; m-half x k-half
// phases, reads 8/4/8/4, stages P1:A-odd(kt+1)->nA, P3:B-h0(kt+2)->cB,
// P4:B-h1(kt+2)->cB + A-even(kt+2)->cA, vmcnt(6)/tile, vmcnt(0) @ NT-2).
// ONLY the LDS-read addressing changed (bisect of R12's failure: R12 also
// moved staging onto global_load_lds's imm-offset arg whose address semantics
// are unverified — staging here stays R11-verbatim with offset arg 0):
//   row&7 == rlane&7 for every frag row (all other row terms are multiples
//   of 8), so the XOR swizzle is a PER-LANE CONSTANT; ks=1 differs from ks=0
//   by per-lane +-64 bytes (bit-6 XOR identity). Hence all 24 reads/tile are
//   loop-invariant base + compile-time literal -> ds_read_b128 offset:N,
//   zero per-read VALU. Verified: pa + i*2048 == R11's FRAG address.
// EPI=0: bf16(gelu(acc*s1)) | EPI=1: f32(acc*s1) | EPI=2: swiglu, 16-col interleave.
template <int EPI, int K>
__global__ __launch_bounds__(512, 1)
void gemm8p(const bf16* __restrict__ A, const bf16* __restrict__ B,
            void* __restrict__ Cout, const float* __restrict__ s1p,
            const float* __restrict__ s2p, int N, int ldh) {
    __shared__ __align__(16) char sm[131072];

    const int tid = threadIdx.x;
    const int w = tid >> 6, l = tid & 63;
    const int wr = w >> 2, wc = w & 3;

    const int gx = gridDim.x;
    const int nwg = gx * (int)gridDim.y;
    const int orig = blockIdx.y * gx + blockIdx.x;
    const int wg = (orig & 7) * (nwg >> 3) + (orig >> 3);
    const int bm = wg / gx, bn = wg % gx;

    constexpr int NT = K / 64;

    f32x4 acc[8][4] = {};

    char* const bufA0 = sm;
    char* const bufB0 = sm + 32768;
    char* const bufA1 = sm + 65536;
    char* const bufB1 = sm + 98304;
    const int arow = bm * 256, brow = bn * 256;

    // ---- staging: R11 VERBATIM (runtime addresses, builtin offset arg = 0)
    const int srow_in = l >> 3;
    const int scolb = ((l & 7) ^ srow_in) << 4;
    auto STAGE = [&](char* ldsT, const bf16* g, int grow0, int kt, int r0) {
        const int rr = r0 + w * 8 + srow_in;
        const char* gp = (const char*)(g + (size_t)(grow0 + rr) * K + kt * 64) + scolb;
        async16(gp, ldsT + r0 * 128 + w * 1024);
    };

    // ---- per-lane LDS read bases (loop-invariant; reads are base + literal)
    const int rlane = l & 15;
    const int chi = (l >> 4) << 4;
    const int sw = (rlane & 7) << 4;
    const int ksd = (rlane & 4) ? -64 : 64;          // (ks=1 col) - (ks=0 col)
    const int offA = (wr * 128 + rlane) * 128 + (chi ^ sw);
    const int offB = (wc * 64 + rlane) * 128 + (chi ^ sw);
    const char* const pA0  = bufA0 + offA;  const char* const pA0k = pA0 + ksd;
    const char* const pB0  = bufB0 + offB;  const char* const pB0k = pB0 + ksd;
    const char* const pA1  = bufA1 + offA;  const char* const pA1k = pA1 + ksd;
    const char* const pB1  = bufB1 + offB;  const char* const pB1k = pB1 + ksd;

    // ---- prologue: tile0 {A-even, B-h0, B-h1, A-odd}; tile1 {A-even, B-h0, B-h1}
    STAGE(bufA0, A, arow, 0, 0);   STAGE(bufA0, A, arow, 0, 128);  // A-even(0)
    STAGE(bufB0, B, brow, 0, 0);   STAGE(bufB0, B, brow, 0, 64);   // B-h0(0)
    STAGE(bufB0, B, brow, 0, 128); STAGE(bufB0, B, brow, 0, 192);  // B-h1(0)
    STAGE(bufA0, A, arow, 0, 64);  STAGE(bufA0, A, arow, 0, 192);  // A-odd(0)
    STAGE(bufA1, A, arow, 1, 0);   STAGE(bufA1, A, arow, 1, 128);  // A-even(1)
    STAGE(bufB1, B, brow, 1, 0);   STAGE(bufB1, B, brow, 1, 64);   // B-h0(1)
    STAGE(bufB1, B, brow, 1, 128); STAGE(bufB1, B, brow, 1, 192);  // B-h1(1)
    asm volatile("s_waitcnt vmcnt(6)" ::: "memory");
    bar();

    auto body = [&](int kt, char* cA, char* cB, char* nA,
                    const char* pa, const char* pak,
                    const char* pb, const char* pbk) {
        bf16x8 ae[4], ao[4], bv[4];
        // ---- P1 (8 reads): avE-ks0 + bv-ks0; stage A-odd(kt+1)->nA
#pragma unroll
        for (int i = 0; i < 4; ++i)
            ae[i] = *reinterpret_cast<const bf16x8*>(pa + i * 2048);
#pragma unroll
        for (int j = 0; j < 4; ++j)
            bv[j] = *reinterpret_cast<const bf16x8*>(pb + j * 2048);
        if (kt + 1 < NT) { STAGE(nA, A, arow, kt + 1, 64); STAGE(nA, A, arow, kt + 1, 192); }
        bar();
        asm volatile("s_waitcnt lgkmcnt(0)" ::: "memory");
        __builtin_amdgcn_sched_barrier(0);
        __builtin_amdgcn_s_setprio(1);
#pragma unroll
        for (int i = 0; i < 4; ++i)
#pragma unroll
            for (int j = 0; j < 4; ++j)
                acc[i][j] = __builtin_amdgcn_mfma_f32_16x16x32_bf16(ae[i], bv[j], acc[i][j], 0, 0, 0);
        __builtin_amdgcn_s_setprio(0);
        bar();
        // ---- P2 (4 reads): avO-ks0
#pragma unroll
        for (int i = 0; i < 4; ++i)
            ao[i] = *reinterpret_cast<const bf16x8*>(pa + 8192 + i * 2048);
        bar();
        asm volatile("s_waitcnt lgkmcnt(0)" ::: "memory");
        __builtin_amdgcn_sched_barrier(0);
        __builtin_amdgcn_s_setprio(1);
#pragma unroll
        for (int i = 0; i < 4; ++i)
#pragma unroll
            for (int j = 0; j < 4; ++j)
                acc[4 + i][j] = __builtin_amdgcn_mfma_f32_16x16x32_bf16(ao[i], bv[j], acc[4 + i][j], 0, 0, 0);
        __builtin_amdgcn_s_setprio(0);
        bar();
        // ---- P3 (8 reads): avE-ks1 + bv-ks1; stage B-h0(kt+2)->cB
#pragma unroll
        for (int i = 0; i < 4; ++i)
            ae[i] = *reinterpret_cast<const bf16x8*>(pak + i * 2048);
#pragma unroll
        for (int j = 0; j < 4; ++j)
            bv[j] = *reinterpret_cast<const bf16x8*>(pbk + j * 2048);
        if (kt + 2 < NT) { STAGE(cB, B, brow, kt + 2, 0); STAGE(cB, B, brow, kt + 2, 64); }
        bar();
        asm volatile("s_waitcnt lgkmcnt(0)" ::: "memory");
        __builtin_amdgcn_sched_barrier(0);
        __builtin_amdgcn_s_setprio(1);
#pragma unroll
        for (int i = 0; i < 4; ++i)
#pragma unroll
            for (int j = 0; j < 4; ++j)
                acc[i][j] = __builtin_amdgcn_mfma_f32_16x16x32_bf16(ae[i], bv[j], acc[i][j], 0, 0, 0);
        __builtin_amdgcn_s_setprio(0);
        bar();
        // ---- P4 (4 reads): avO-ks1; stage B-h1(kt+2)->cB + A-even(kt+2)->cA
#pragma unroll
        for (int i = 0; i < 4; ++i)
            ao[i] = *reinterpret_cast<const bf16x8*>(pak + 8192 + i * 2048);
        if (kt + 2 < NT) {
            STAGE(cB, B, brow, kt + 2, 128); STAGE(cB, B, brow, kt + 2, 192);
            STAGE(cA, A, arow, kt + 2, 0);   STAGE(cA, A, arow, kt + 2, 128);
        }
        bar();
        asm volatile("s_waitcnt lgkmcnt(0)" ::: "memory");
        __builtin_amdgcn_sched_barrier(0);
        __builtin_amdgcn_s_setprio(1);
#pragma unroll
        for (int i = 0; i < 4; ++i)
#pragma unroll
            for (int j = 0; j < 4; ++j)
                acc[4 + i][j] = __builtin_amdgcn_mfma_f32_16x16x32_bf16(ao[i], bv[j], acc[4 + i][j], 0, 0, 0);
        __builtin_amdgcn_s_setprio(0);
        if (kt == NT - 2) { asm volatile("s_waitcnt vmcnt(0)" ::: "memory"); }
        else              { asm volatile("s_waitcnt vmcnt(6)" ::: "memory"); }
        bar();
    };

#pragma unroll 1
    for (int kt = 0; kt < NT; kt += 2) {
        body(kt,     bufA0, bufB0, bufA1, pA0, pA0k, pB0, pB0k);
        body(kt + 1, bufA1, bufB1, bufA0, pA1, pA1k, pB1, pB1k);
    }

    const float s1 = s1p[0];
    const int r0 = bm * 256 + wr * 128 + ((l >> 4) << 2);
    if constexpr (EPI == 2) {
        const float s2 = s2p[0];
        const int hcb = (bn * 8 + wc * 2) * 16 + rlane;
#pragma unroll
        for (int i = 0; i < 8; ++i)
#pragma unroll
            for (int jp = 0; jp < 2; ++jp)
#pragma unroll
                for (int q = 0; q < 4; ++q) {
                    float g = acc[i][2 * jp][q] * s1;
                    float v = acc[i][2 * jp + 1][q] * s2;
                    float sig = 1.0f / (1.0f + __expf(-g));
                    ((bf16*)Cout)[(size_t)(r0 + i * 16 + q) * ldh + hcb + jp * 16] =
                        (bf16)(g * sig * v);
                }
    } else {
        const int c0 = bn * 256 + wc * 64 + rlane;
#pragma unroll
        for (int i = 0; i < 8; ++i)
#pragma unroll
            for (int j = 0; j < 4; ++j)
#pragma unroll
                for (int q = 0; q < 4; ++q) {
                    float v = acc[i][j][q] * s1;
                    size_t idx = (size_t)(r0 + i * 16 + q) * N + (c0 + j * 16);
                    if constexpr (EPI == 0) {
                        float g = 0.5f * v * (1.0f + erff(v * 0.70710678118654752f));
                        ((bf16*)Cout)[idx] = (bf16)g;
                    } else {
                        ((float*)Cout)[idx] = v;
                    }
                }
    }
}

// ---------------------------------------------------------------- launch
extern "C" void kernel_launch(void* const* d_in, const int* in_sizes, int n_in,
                              void* d_out, int out_size, void* d_ws, size_t ws_size,
                              hipStream_t stream) {
    constexpr int NTOK = 8192, DIN = 2048, DHID = 8192;

    const float* x  = (const float*)d_in[0];
    const float* W1 = (const float*)d_in[1];
    const float* W2 = (const float*)d_in[2];
    const float* Wh = (const float*)d_in[3];
    const float* W3 = (const float*)d_in[4];
    const float* s1 = (const float*)d_in[5];
    const float* s2 = (const float*)d_in[6];
    const float* sh = (const float*)d_in[7];
    const float* s3 = (const float*)d_in[8];
    float* out = (float*)d_out;

    char* ws = (char*)d_ws;
    size_t off = 0;
    bf16* xb   = (bf16*)(ws + off); off += (size_t)NTOK * DIN * 2;
    bf16* w12b = (bf16*)(ws + off); off += (size_t)2 * DHID * DIN * 2;
    bf16* w3b  = (bf16*)(ws + off); off += (size_t)DIN * DHID * 2;
    bf16* whb  = (bf16*)(ws + off); off += (size_t)DHID * DHID * 2;
    bf16* h1   = (bf16*)(ws + off); off += (size_t)NTOK * DHID * 2;
    bf16* h2   = (bf16*)(ws + off); off += (size_t)NTOK * DHID * 2;
    if (ws_size < off) return;

    auto cvt = [&](const float* s, bf16* d, size_t n) {
        int n8 = (int)(n / 8);
        cvt_f32_bf16_kernel<<<(n8 + 255) / 256, 256, 0, stream>>>(s, d, n8);
    };
    cvt(x,  xb,  (size_t)NTOK * DIN);
    cvt(Wh, whb, (size_t)DHID * DHID);
    cvt(W3, w3b, (size_t)DIN * DHID);
    {
        int n8 = (int)((size_t)DHID * DIN / 8);
        cvt_ilv_kernel<<<(n8 + 255) / 256, 256, 0, stream>>>(W1, w12b, n8, 0);
        cvt_ilv_kernel<<<(n8 + 255) / 256, 256, 0, stream>>>(W2, w12b, n8, 1);
    }

    // GEMM1+2 fused: C[8192, 16384] over interleaved W12, SwiGLU epilogue -> h1
    gemm8p<2, DIN><<<dim3(2 * DHID / 256, NTOK / 256), 512, 0, stream>>>(
        xb, w12b, h1, s1, s2, 2 * DHID, DHID);
    // hidden GEMM + gelu -> h2
    gemm8p<0, DHID><<<dim3(DHID / 256, NTOK / 256), 512, 0, stream>>>(
        h1, whb, h2, sh, sh, DHID, DHID);
    // output GEMM -> out (f32)
    gemm8p<1, DHID><<<dim3(DIN / 256, NTOK / 256), 512, 0, stream>>>(
        h2, w3b, out, s3, s3, DIN, DIN);
}